// Round 9
// baseline (313.560 us; speedup 1.0000x reference)
//
#include <hip/hip_runtime.h>
#include <stdint.h>

#define S_LEN 2048
#define HID   3584
#define NH    28
#define NKV   4
#define HD    128
#define NQKV  4608   // 3584 + 512 + 512
#define GRP   7      // NH / NKV

typedef float  f32x4  __attribute__((ext_vector_type(4)));
typedef __bf16 bf16x8 __attribute__((ext_vector_type(8)));
typedef __bf16 bf16x4 __attribute__((ext_vector_type(4)));

#define GLOAD_LDS16(gp, lp) \
  __builtin_amdgcn_global_load_lds((const __attribute__((address_space(1))) void*)(gp), \
                                   (__attribute__((address_space(3))) void*)(lp), 16, 0, 0)

// ---------------- fused conversions: all f32->bf16 regions + bias concat ----------------
__global__ void cvt_all(const float* __restrict__ hidden, const float* __restrict__ qw,
                        const float* __restrict__ kw, const float* __restrict__ vw,
                        const float* __restrict__ ow,
                        const float* __restrict__ qb, const float* __restrict__ kb,
                        const float* __restrict__ vb,
                        __bf16* __restrict__ hid_bf, __bf16* __restrict__ Wqkv,
                        __bf16* __restrict__ ow_bf, float* __restrict__ bias)
{
  const int i = blockIdx.x * blockDim.x + threadIdx.x;
  if (i < NQKV) {
    float v = (i < HID) ? qb[i] : (i < HID + 512) ? kb[i - HID] : vb[i - HID - 512];
    bias[i] = v;
  }
  const int n_hid = S_LEN * HID / 8;   // 917504
  const int n_qw  = HID * HID / 8;     // 1605632
  const int n_kw  = 512 * HID / 8;     // 229376
  const int N0 = n_hid, N1 = N0 + n_qw, N2 = N1 + n_kw, N3 = N2 + n_kw, N4 = N3 + n_qw;
  if (i >= N4) return;
  const float* src; __bf16* dst; int off;
  if (i < N0)      { src = hidden; dst = hid_bf;                              off = i; }
  else if (i < N1) { src = qw;     dst = Wqkv;                                off = i - N0; }
  else if (i < N2) { src = kw;     dst = Wqkv + (size_t)HID * HID;            off = i - N1; }
  else if (i < N3) { src = vw;     dst = Wqkv + (size_t)(HID + 512) * HID;    off = i - N2; }
  else             { src = ow;     dst = ow_bf;                               off = i - N3; }
  const float4 a = *(const float4*)(src + (size_t)off * 8);
  const float4 b = *(const float4*)(src + (size_t)off * 8 + 4);
  bf16x8 o;
  o[0] = (__bf16)a.x; o[1] = (__bf16)a.y; o[2] = (__bf16)a.z; o[3] = (__bf16)a.w;
  o[4] = (__bf16)b.x; o[5] = (__bf16)b.y; o[6] = (__bf16)b.z; o[7] = (__bf16)b.w;
  *(bf16x8*)(dst + (size_t)off * 8) = o;
}

// ---------------- GEMM core tile params ----------------
#define BM 128
#define BN 128
#define BK 64

// ---------------- plain GEMM (O-projection): C = A * B^T (+bias), f32 out ----------------
template <typename OutT>
__global__ __launch_bounds__(256) void gemm_bt(
    const __bf16* __restrict__ A, const __bf16* __restrict__ B,
    const float* __restrict__ bias, OutT* __restrict__ C,
    int M, int N, int K)
{
  __shared__ __bf16 As[BM * BK];
  __shared__ __bf16 Bs[BN * BK];

  const int t    = threadIdx.x;
  const int lane = t & 63;
  const int w    = t >> 6;
  const int wm   = w >> 1;
  const int wn   = w & 1;
  const int row0 = blockIdx.y * BM;
  const int col0 = blockIdx.x * BN;
  const int lq   = lane & 15;
  const int lg   = lane >> 4;

  const int sr  = lane >> 3;
  const int sch = (lane & 7) ^ (sr & 7);
  const __bf16* aG = A + (size_t)(row0 + w * 32 + sr) * K + sch * 8;
  const __bf16* bG = B + (size_t)(col0 + w * 32 + sr) * K + sch * 8;
  __bf16* asW = As + w * 2048;
  __bf16* bsW = Bs + w * 2048;

  f32x4 acc[4][4];
#pragma unroll
  for (int i = 0; i < 4; ++i)
#pragma unroll
    for (int j = 0; j < 4; ++j) { acc[i][j][0]=0.f; acc[i][j][1]=0.f; acc[i][j][2]=0.f; acc[i][j][3]=0.f; }

  for (int kt = 0; kt < K; kt += BK) {
    __syncthreads();
#pragma unroll
    for (int seg = 0; seg < 4; ++seg) {
      GLOAD_LDS16(aG + (size_t)seg * 8 * K + kt, asW + seg * 512);
      GLOAD_LDS16(bG + (size_t)seg * 8 * K + kt, bsW + seg * 512);
    }
    __syncthreads();

#pragma unroll
    for (int kk = 0; kk < 2; ++kk) {
      const int ch = kk * 4 + lg;
      bf16x8 af[4], bfr[4];
#pragma unroll
      for (int mf = 0; mf < 4; ++mf) {
        int r = wm * 64 + mf * 16 + lq;
        af[mf] = *(const bf16x8*)(As + r * BK + ((ch ^ (r & 7)) * 8));
      }
#pragma unroll
      for (int nf = 0; nf < 4; ++nf) {
        int r = wn * 64 + nf * 16 + lq;
        bfr[nf] = *(const bf16x8*)(Bs + r * BK + ((ch ^ (r & 7)) * 8));
      }
#pragma unroll
      for (int mf = 0; mf < 4; ++mf)
#pragma unroll
        for (int nf = 0; nf < 4; ++nf)
          acc[mf][nf] = __builtin_amdgcn_mfma_f32_16x16x32_bf16(af[mf], bfr[nf], acc[mf][nf], 0, 0, 0);
    }
  }

#pragma unroll
  for (int mf = 0; mf < 4; ++mf) {
#pragma unroll
    for (int nf = 0; nf < 4; ++nf) {
      int col = col0 + wn * 64 + nf * 16 + lq;
      float bv = bias ? bias[col] : 0.0f;
#pragma unroll
      for (int r = 0; r < 4; ++r) {
        int rowg = row0 + wm * 64 + mf * 16 + lg * 4 + r;
        C[(size_t)rowg * N + col] = (OutT)(acc[mf][nf][r] + bv);
      }
    }
  }
}

// ---------------- QKV GEMM with fused bias + RoPE + scatter epilogue ----------------
// Same 128x128 core; epilogue dumps biased C-tile to padded LDS [128][136],
// then 256 threads apply RoPE (Q/K blocks) or transpose-scatter (V blocks).
__global__ __launch_bounds__(256) void gemm_qkv(
    const __bf16* __restrict__ A, const __bf16* __restrict__ B,
    const float* __restrict__ bias,
    const float* __restrict__ cosb, const float* __restrict__ sinb,
    __bf16* __restrict__ Qo, __bf16* __restrict__ Ko, __bf16* __restrict__ Vt)
{
  __shared__ __bf16 smem[128 * 136];   // 34.8 KB; K-loop uses first 32 KB
  __bf16* As = smem;
  __bf16* Bs = smem + BM * BK;

  const int K = HID;
  const int t    = threadIdx.x;
  const int lane = t & 63;
  const int w    = t >> 6;
  const int wm   = w >> 1;
  const int wn   = w & 1;
  const int row0 = blockIdx.y * BM;
  const int col0 = blockIdx.x * BN;
  const int lq   = lane & 15;
  const int lg   = lane >> 4;

  const int sr  = lane >> 3;
  const int sch = (lane & 7) ^ (sr & 7);
  const __bf16* aG = A + (size_t)(row0 + w * 32 + sr) * K + sch * 8;
  const __bf16* bG = B + (size_t)(col0 + w * 32 + sr) * K + sch * 8;
  __bf16* asW = As + w * 2048;
  __bf16* bsW = Bs + w * 2048;

  f32x4 acc[4][4];
#pragma unroll
  for (int i = 0; i < 4; ++i)
#pragma unroll
    for (int j = 0; j < 4; ++j) { acc[i][j][0]=0.f; acc[i][j][1]=0.f; acc[i][j][2]=0.f; acc[i][j][3]=0.f; }

  for (int kt = 0; kt < K; kt += BK) {
    __syncthreads();
#pragma unroll
    for (int seg = 0; seg < 4; ++seg) {
      GLOAD_LDS16(aG + (size_t)seg * 8 * K + kt, asW + seg * 512);
      GLOAD_LDS16(bG + (size_t)seg * 8 * K + kt, bsW + seg * 512);
    }
    __syncthreads();

#pragma unroll
    for (int kk = 0; kk < 2; ++kk) {
      const int ch = kk * 4 + lg;
      bf16x8 af[4], bfr[4];
#pragma unroll
      for (int mf = 0; mf < 4; ++mf) {
        int r = wm * 64 + mf * 16 + lq;
        af[mf] = *(const bf16x8*)(As + r * BK + ((ch ^ (r & 7)) * 8));
      }
#pragma unroll
      for (int nf = 0; nf < 4; ++nf) {
        int r = wn * 64 + nf * 16 + lq;
        bfr[nf] = *(const bf16x8*)(Bs + r * BK + ((ch ^ (r & 7)) * 8));
      }
#pragma unroll
      for (int mf = 0; mf < 4; ++mf)
#pragma unroll
        for (int nf = 0; nf < 4; ++nf)
          acc[mf][nf] = __builtin_amdgcn_mfma_f32_16x16x32_bf16(af[mf], bfr[nf], acc[mf][nf], 0, 0, 0);
    }
  }

  // ---- epilogue: dump biased tile to LDS ----
  __syncthreads();   // all waves done reading As/Bs
#pragma unroll
  for (int mf = 0; mf < 4; ++mf) {
#pragma unroll
    for (int nf = 0; nf < 4; ++nf) {
      const int c_loc = wn * 64 + nf * 16 + lq;
      const float bv = bias[col0 + c_loc];
#pragma unroll
      for (int r = 0; r < 4; ++r) {
        const int s_loc = wm * 64 + mf * 16 + lg * 4 + r;
        smem[s_loc * 136 + c_loc] = (__bf16)(acc[mf][nf][r] + bv);
      }
    }
  }
  __syncthreads();

  // ---- rope (Q/K) or transpose (V) scatter ----
  if (col0 < 4096) {
    const int s_loc = t >> 1;
    const int dh    = (t & 1) << 6;     // 0 or 64
    const int s_g   = row0 + s_loc;
    __bf16* P = (col0 < HID)
        ? (Qo + ((size_t)(col0 >> 7) * S_LEN + s_g) * HD)
        : (Ko + ((size_t)((col0 - HID) >> 7) * S_LEN + s_g) * HD);
    const float sgn = (t & 1) ? 1.0f : -1.0f;
#pragma unroll
    for (int j = 0; j < 8; ++j) {
      const int d = dh + j * 8;
      const int axis = (d < 16) ? 0 : (d < 40) ? 1 : (d < 64) ? 2
                     : (d < 80) ? 0 : (d < 104) ? 1 : 2;
      const float* cp = cosb + ((size_t)axis * S_LEN + s_g) * HD + d;
      const float* sp = sinb + ((size_t)axis * S_LEN + s_g) * HD + d;
      const bf16x8 x = *(const bf16x8*)&smem[s_loc * 136 + d];
      const bf16x8 p = *(const bf16x8*)&smem[s_loc * 136 + (d ^ 64)];
      bf16x8 o;
#pragma unroll
      for (int jj = 0; jj < 8; ++jj)
        o[jj] = (__bf16)((float)x[jj] * cp[jj] + sgn * (float)p[jj] * sp[jj]);
      *(bf16x8*)(P + d) = o;
    }
  } else {
    const int d_loc = t >> 1;
    const int sh    = (t & 1) << 6;
    const int kh    = (col0 - 4096) >> 7;
    __bf16* P = Vt + ((size_t)kh * HD + d_loc) * S_LEN + row0 + sh;
#pragma unroll
    for (int j = 0; j < 8; ++j) {
      bf16x8 o;
#pragma unroll
      for (int jj = 0; jj < 8; ++jj)
        o[jj] = smem[(sh + j * 8 + jj) * 136 + d_loc];
      *(bf16x8*)(P + j * 8) = o;
    }
  }
}

// ---- KV-split piece table: 24 (qtile, seg) pieces per head, heavy-first ----
__device__ const unsigned char SEG_QT[24] = {7,8,9,10,11,12,13,14,15,15,14,6,13,5,12,4,11,3,10,2,9,1,8,0};
__device__ const unsigned char SEG_SG[24] = {0,0,0,0, 0, 0, 0, 0, 0, 1, 1,0, 1,0, 1,0, 1,0, 1,0,1,0,1,0};

// ---------------- Flash attention (KV-split, defer-max, lane-local softmax) ----------------
__global__ __launch_bounds__(512, 4) void attn_fwd(
    const __bf16* __restrict__ Q, const __bf16* __restrict__ K,
    const __bf16* __restrict__ Vt, __bf16* __restrict__ Opart,
    float* __restrict__ mlbuf)
{
  __shared__ __bf16 Ks[2][64 * HD];
  __shared__ __bf16 Vs[2][HD * 64];

  const int t     = threadIdx.x;
  const int lane  = t & 63;
  const int w     = t >> 6;
  const int pid   = blockIdx.x / NH;
  const int h     = blockIdx.x % NH;
  const int qtile = SEG_QT[pid];
  const int seg   = SEG_SG[pid];
  const int kvh   = h / GRP;
  const int q0w   = qtile * 128 + w * 16;
  const int lq    = lane & 15;
  const int lg    = lane >> 4;

  const int nkt_full = 2 * qtile + 2;
  const int kt0 = seg * 16;
  const int kt1 = (nkt_full < kt0 + 16) ? nkt_full : (kt0 + 16);

  const __bf16* Kbase = K  + (size_t)kvh * S_LEN * HD;
  const __bf16* Vbase = Vt + (size_t)kvh * HD * S_LEN;

  const int krow_in = lane >> 4;
  const int kch     = lane & 15;
  const int vrow_in = lane >> 3;
  const int vch     = lane & 7;

  bf16x8 qf[4];
  {
    const __bf16* qp = Q + ((size_t)h * S_LEN + q0w + lq) * HD + lg * 8;
#pragma unroll
    for (int dd = 0; dd < 4; ++dd) qf[dd] = *(const bf16x8*)(qp + dd * 32);
  }

  f32x4 of[8];
#pragma unroll
  for (int i = 0; i < 8; ++i) { of[i][0]=0.f; of[i][1]=0.f; of[i][2]=0.f; of[i][3]=0.f; }
  float m_run = -1e30f;
  float lsum  = 0.0f;

  const float kscale = 0.08838834764831845f * 1.4426950408889634f;
  const float THR = 11.0f;

  const int srcA = lq + 16 * ((2 * lg) & 3);
  const int srcB = lq + 16 * ((2 * lg + 1) & 3);
  const bool hisel = (lg >> 1) != 0;

#define STAGE_KV(ktile, b)                                                       \
  {                                                                              \
    _Pragma("unroll")                                                            \
    for (int j = 0; j < 2; ++j) {                                                \
      int rr = j * 32 + w * 4 + krow_in;                                         \
      int sc = kch ^ (rr & 15);                                                  \
      GLOAD_LDS16(Kbase + (size_t)((ktile) * 64 + rr) * HD + sc * 8,             \
                  &Ks[b][(j * 32 + w * 4) * HD]);                                \
    }                                                                            \
    _Pragma("unroll")                                                            \
    for (int j = 0; j < 2; ++j) {                                                \
      int rr = j * 64 + w * 8 + vrow_in;                                         \
      int sc = vch ^ (rr & 7);                                                   \
      GLOAD_LDS16(Vbase + (size_t)rr * S_LEN + (ktile) * 64 + sc * 8,            \
                  &Vs[b][(j * 64 + w * 8) * 64]);                                \
    }                                                                            \
  }

  STAGE_KV(kt0, 0);
  __syncthreads();

  int cur = 0;
  for (int kt = kt0; kt < kt1; ++kt) {
    if (kt + 1 < kt1) STAGE_KV(kt + 1, cur ^ 1);

    const bool active = (kt * 64) <= (q0w + 15);
    if (active) {
      const __bf16* KsC = &Ks[cur][0];
      const __bf16* VsC = &Vs[cur][0];

      f32x4 sf[4];
      __builtin_amdgcn_s_setprio(1);
#pragma unroll
      for (int kb = 0; kb < 4; ++kb) {
        sf[kb][0]=0.f; sf[kb][1]=0.f; sf[kb][2]=0.f; sf[kb][3]=0.f;
#pragma unroll
        for (int dd = 0; dd < 4; ++dd) {
          int r  = kb * 16 + lq;
          int ch = dd * 4 + lg;
          bf16x8 kf = *(const bf16x8*)(KsC + r * HD + ((ch ^ (r & 15)) * 8));
          sf[kb] = __builtin_amdgcn_mfma_f32_16x16x32_bf16(kf, qf[dd], sf[kb], 0, 0, 0);
        }
      }
      __builtin_amdgcn_s_setprio(0);

      const int qg = q0w + lq;
      const bool diag = (kt * 64 + 63) > q0w;
      float pmax = -1e30f;
#pragma unroll
      for (int kb = 0; kb < 4; ++kb) {
#pragma unroll
        for (int r = 0; r < 4; ++r) {
          float v = sf[kb][r] * kscale;
          if (diag) {
            int kg = kt * 64 + kb * 16 + lg * 4 + r;
            if (kg > qg) v = -1e30f;
          }
          sf[kb][r] = v;
          pmax = fmaxf(pmax, v);
        }
      }

      if (__any(pmax > m_run + THR)) {
        float pm = fmaxf(pmax, __shfl_xor(pmax, 16));
        pm = fmaxf(pm, __shfl_xor(pm, 32));
        const float mn = fmaxf(m_run, pm);
        const float e = exp2f(m_run - mn);
        m_run = mn;
        lsum *= e;
#pragma unroll
        for (int db = 0; db < 8; ++db) {
          of[db][0] *= e; of[db][1] *= e; of[db][2] *= e; of[db][3] *= e;
        }
      }

      float ps = 0.0f;
      uint32_t pk[4][2];
#pragma unroll
      for (int kb = 0; kb < 4; ++kb) {
        float p0 = exp2f(sf[kb][0] - m_run);
        float p1 = exp2f(sf[kb][1] - m_run);
        float p2 = exp2f(sf[kb][2] - m_run);
        float p3 = exp2f(sf[kb][3] - m_run);
        ps += (p0 + p1) + (p2 + p3);
        unsigned short b0 = __builtin_bit_cast(unsigned short, (__bf16)p0);
        unsigned short b1 = __builtin_bit_cast(unsigned short, (__bf16)p1);
        unsigned short b2 = __builtin_bit_cast(unsigned short, (__bf16)p2);
        unsigned short b3 = __builtin_bit_cast(unsigned short, (__bf16)p3);
        pk[kb][0] = (uint32_t)b0 | ((uint32_t)b1 << 16);
        pk[kb][1] = (uint32_t)b2 | ((uint32_t)b3 << 16);
      }
      lsum += ps;

      __builtin_amdgcn_s_setprio(1);
#pragma unroll
      for (int kc = 0; kc < 2; ++kc) {
        uint32_t a0 = __shfl((int)pk[kc * 2][0],     srcA);
        uint32_t a1 = __shfl((int)pk[kc * 2][1],     srcA);
        uint32_t b0 = __shfl((int)pk[kc * 2 + 1][0], srcA);
        uint32_t b1 = __shfl((int)pk[kc * 2 + 1][1], srcA);
        uint32_t c0 = __shfl((int)pk[kc * 2][0],     srcB);
        uint32_t c1 = __shfl((int)pk[kc * 2][1],     srcB);
        uint32_t d0 = __shfl((int)pk[kc * 2 + 1][0], srcB);
        uint32_t d1 = __shfl((int)pk[kc * 2 + 1][1], srcB);
        uint4 pu;
        pu.x = hisel ? b0 : a0;
        pu.y = hisel ? b1 : a1;
        pu.z = hisel ? d0 : c0;
        pu.w = hisel ? d1 : c1;
        bf16x8 pfrag = __builtin_bit_cast(bf16x8, pu);
#pragma unroll
        for (int db = 0; db < 8; ++db) {
          int vr = db * 16 + lq;
          int vc = kc * 4 + lg;
          bf16x8 vf = *(const bf16x8*)(VsC + vr * 64 + ((vc ^ (vr & 7)) * 8));
          of[db] = __builtin_amdgcn_mfma_f32_16x16x32_bf16(vf, pfrag, of[db], 0, 0, 0);
        }
      }
      __builtin_amdgcn_s_setprio(0);
    }

    __syncthreads();
    cur ^= 1;
  }
#undef STAGE_KV

  lsum += __shfl_xor(lsum, 16);
  lsum += __shfl_xor(lsum, 32);
  const float rl = 1.0f / lsum;
  const int q = q0w + lq;
  const size_t pbase = ((size_t)h * S_LEN + q) * 2 + seg;
  __bf16* op = Opart + pbase * HD + lg * 4;
#pragma unroll
  for (int db = 0; db < 8; ++db) {
    bf16x4 o4;
    o4[0] = (__bf16)(of[db][0] * rl);
    o4[1] = (__bf16)(of[db][1] * rl);
    o4[2] = (__bf16)(of[db][2] * rl);
    o4[3] = (__bf16)(of[db][3] * rl);
    *(bf16x4*)(op + db * 16) = o4;
  }
  if (lg == 0) {
    mlbuf[pbase * 2]     = m_run;
    mlbuf[pbase * 2 + 1] = lsum;
  }
}

// ---------------- combine partial attention outputs ----------------
__global__ __launch_bounds__(256) void attn_combine(
    const __bf16* __restrict__ Opart, const float* __restrict__ mlbuf,
    __bf16* __restrict__ Ao)
{
  const int gw   = (blockIdx.x * 256 + threadIdx.x) >> 6;
  const int lane = threadIdx.x & 63;
  if (gw >= NH * S_LEN) return;
  const int h  = gw >> 11;
  const int q  = gw & 2047;
  const int qt = q >> 7;
  const size_t base = ((size_t)h * S_LEN + q) * 2;

  const uint32_t x0 = ((const uint32_t*)(Opart + base * HD))[lane];
  const float lo0 = (float)__builtin_bit_cast(__bf16, (unsigned short)(x0 & 0xffff));
  const float hi0 = (float)__builtin_bit_cast(__bf16, (unsigned short)(x0 >> 16));

  float olo, ohi;
  if (qt >= 8) {
    const float m0 = mlbuf[base * 2],       l0 = mlbuf[base * 2 + 1];
    const float m1 = mlbuf[(base + 1) * 2], l1 = mlbuf[(base + 1) * 2 + 1];
    const uint32_t x1 = ((const uint32_t*)(Opart + (base + 1) * HD))[lane];
    const float lo1 = (float)__builtin_bit_cast(__bf16, (unsigned short)(x1 & 0xffff));
    const float hi1 = (float)__builtin_bit_cast(__bf16, (unsigned short)(x1 >> 16));
    const float M  = fmaxf(m0, m1);
    const float w0 = l0 * exp2f(m0 - M);
    const float w1 = l1 * exp2f(m1 - M);
    const float rs = 1.0f / (w0 + w1);
    olo = (w0 * lo0 + w1 * lo1) * rs;
    ohi = (w0 * hi0 + w1 * hi1) * rs;
  } else {
    olo = lo0; ohi = hi0;
  }

  const unsigned short blo = __builtin_bit_cast(unsigned short, (__bf16)olo);
  const unsigned short bhi = __builtin_bit_cast(unsigned short, (__bf16)ohi);
  ((uint32_t*)(Ao + (size_t)q * HID + h * HD))[lane] =
      (uint32_t)blo | ((uint32_t)bhi << 16);
}

// ---------------- launch ----------------
extern "C" void kernel_launch(void* const* d_in, const int* in_sizes, int n_in,
                              void* d_out, int out_size, void* d_ws, size_t ws_size,
                              hipStream_t stream) {
  const float* hidden = (const float*)d_in[0];
  const float* cosb   = (const float*)d_in[1];
  const float* sinb   = (const float*)d_in[2];
  const float* q_w = (const float*)d_in[4];
  const float* q_b = (const float*)d_in[5];
  const float* k_w = (const float*)d_in[6];
  const float* k_b = (const float*)d_in[7];
  const float* v_w = (const float*)d_in[8];
  const float* v_b = (const float*)d_in[9];
  const float* o_w = (const float*)d_in[10];
  float* out = (float*)d_out;

  char* ws = (char*)d_ws;
  size_t off = 0;
  auto alloc = [&](size_t bytes) {
    off = (off + 255) & ~(size_t)255;
    void* p = ws + off;
    off += bytes;
    return p;
  };

  __bf16* hid_bf  = (__bf16*)alloc((size_t)S_LEN * HID * 2);
  __bf16* Wqkv    = (__bf16*)alloc((size_t)NQKV * HID * 2);
  float*  bias    = (float*) alloc((size_t)NQKV * 4);
  __bf16* Qb      = (__bf16*)alloc((size_t)NH * S_LEN * HD * 2);
  __bf16* Kb      = (__bf16*)alloc((size_t)NKV * S_LEN * HD * 2);
  __bf16* Vtb     = (__bf16*)alloc((size_t)NKV * HD * S_LEN * 2);
  __bf16* attn_o  = (__bf16*)alloc((size_t)S_LEN * HID * 2);
  __bf16* ow_bf   = (__bf16*)alloc((size_t)HID * HID * 2);

  // KV-split partial buffers overlay hid_bf/Wqkv (dead once attn_fwd runs).
  // Opart: 29.4 MB at ws+0; mlbuf (1.9 MB) at ws+34MB — both inside the
  // hid_bf+Wqkv region (47.7 MB), disjoint from Qb onward.
  __bf16* Opart = (__bf16*)(ws);
  float*  mlbuf = (float*)(ws + ((size_t)34 << 20));

  const int TB = 256;
  auto cdiv = [](int a, int b) { return (a + b - 1) / b; };

  // fused conversions + bias concat (single launch)
  {
    const int n8 = (S_LEN * HID + 2 * HID * HID + 2 * 512 * HID) / 8;
    cvt_all<<<cdiv(n8, TB), TB, 0, stream>>>(hidden, q_w, k_w, v_w, o_w,
                                             q_b, k_b, v_b,
                                             hid_bf, Wqkv, ow_bf, bias);
  }

  // QKV projection with fused bias + RoPE + Q/K/V^T scatter
  {
    dim3 grid(NQKV / BN, S_LEN / BM);
    gemm_qkv<<<grid, TB, 0, stream>>>(hid_bf, Wqkv, bias, cosb, sinb, Qb, Kb, Vtb);
  }

  // flash attention: KV-split pieces (24 per head), heavy-first
  attn_fwd<<<24 * NH, 512, 0, stream>>>(Qb, Kb, Vtb, Opart, mlbuf);

  // merge partials
  attn_combine<<<cdiv(NH * S_LEN, 4), TB, 0, stream>>>(Opart, mlbuf, attn_o);

  // output projection (f32 out)
  {
    dim3 grid(HID / BN, S_LEN / BM);
    gemm_bt<float><<<grid, TB, 0, stream>>>(attn_o, ow_bf, nullptr, out, S_LEN, HID, HID);
  }
}

// Round 10
// 282.265 us; speedup vs baseline: 1.1109x; 1.1109x over previous
//
#include <hip/hip_runtime.h>
#include <stdint.h>

#define S_LEN 2048
#define HID   3584
#define NH    28
#define NKV   4
#define HD    128
#define NQKV  4608   // 3584 + 512 + 512
#define GRP   7      // NH / NKV

typedef float  f32x4  __attribute__((ext_vector_type(4)));
typedef __bf16 bf16x8 __attribute__((ext_vector_type(8)));
typedef __bf16 bf16x4 __attribute__((ext_vector_type(4)));

#define GLOAD_LDS16(gp, lp) \
  __builtin_amdgcn_global_load_lds((const __attribute__((address_space(1))) void*)(gp), \
                                   (__attribute__((address_space(3))) void*)(lp), 16, 0, 0)

// ---------------- fused conversions: f32->bf16 + bias concat + rope table ----------------
// Also builds axis-resolved bf16 cos/sin tables: cs[s][d] with mrope axis folded in.
__global__ void cvt_all(const float* __restrict__ hidden, const float* __restrict__ qw,
                        const float* __restrict__ kw, const float* __restrict__ vw,
                        const float* __restrict__ ow,
                        const float* __restrict__ qb, const float* __restrict__ kb,
                        const float* __restrict__ vb,
                        const float* __restrict__ cosb, const float* __restrict__ sinb,
                        __bf16* __restrict__ hid_bf, __bf16* __restrict__ Wqkv,
                        __bf16* __restrict__ ow_bf, float* __restrict__ bias,
                        __bf16* __restrict__ cosbf, __bf16* __restrict__ sinbf)
{
  const int i = blockIdx.x * blockDim.x + threadIdx.x;
  if (i < NQKV) {
    float v = (i < HID) ? qb[i] : (i < HID + 512) ? kb[i - HID] : vb[i - HID - 512];
    bias[i] = v;
  }
  const int n_hid = S_LEN * HID / 8;
  const int n_qw  = HID * HID / 8;
  const int n_kw  = 512 * HID / 8;
  const int N0 = n_hid, N1 = N0 + n_qw, N2 = N1 + n_kw, N3 = N2 + n_kw, N4 = N3 + n_qw;
  const int N5 = N4 + S_LEN * 16;   // rope table chunks (16 per row: d8 in [0,16))

  if (i >= N5) return;
  if (i >= N4) {
    // rope table: s = off>>4, d = (off&15)*8; axis uniform per 8-chunk
    const int off = i - N4;
    const int s = off >> 4;
    const int d = (off & 15) * 8;
    const int axis = (d < 16) ? 0 : (d < 40) ? 1 : (d < 64) ? 2
                   : (d < 80) ? 0 : (d < 104) ? 1 : 2;
    const float* cp = cosb + ((size_t)axis * S_LEN + s) * HD + d;
    const float* sp = sinb + ((size_t)axis * S_LEN + s) * HD + d;
    bf16x8 oc, os;
#pragma unroll
    for (int j = 0; j < 8; ++j) { oc[j] = (__bf16)cp[j]; os[j] = (__bf16)sp[j]; }
    *(bf16x8*)(cosbf + (size_t)s * HD + d) = oc;
    *(bf16x8*)(sinbf + (size_t)s * HD + d) = os;
    return;
  }
  const float* src; __bf16* dst; int off;
  if (i < N0)      { src = hidden; dst = hid_bf;                              off = i; }
  else if (i < N1) { src = qw;     dst = Wqkv;                                off = i - N0; }
  else if (i < N2) { src = kw;     dst = Wqkv + (size_t)HID * HID;            off = i - N1; }
  else if (i < N3) { src = vw;     dst = Wqkv + (size_t)(HID + 512) * HID;    off = i - N2; }
  else             { src = ow;     dst = ow_bf;                               off = i - N3; }
  const float4 a = *(const float4*)(src + (size_t)off * 8);
  const float4 b = *(const float4*)(src + (size_t)off * 8 + 4);
  bf16x8 o;
  o[0] = (__bf16)a.x; o[1] = (__bf16)a.y; o[2] = (__bf16)a.z; o[3] = (__bf16)a.w;
  o[4] = (__bf16)b.x; o[5] = (__bf16)b.y; o[6] = (__bf16)b.z; o[7] = (__bf16)b.w;
  *(bf16x8*)(dst + (size_t)off * 8) = o;
}

// ---------------- GEMM: C[M][N] = A[M][K] * B[N][K]^T + bias ----------------
#define BM 128
#define BN 128
#define BK 64

template <typename OutT>
__global__ __launch_bounds__(256) void gemm_bt(
    const __bf16* __restrict__ A, const __bf16* __restrict__ B,
    const float* __restrict__ bias, OutT* __restrict__ C,
    int M, int N, int K)
{
  __shared__ __bf16 As[BM * BK];
  __shared__ __bf16 Bs[BN * BK];

  const int t    = threadIdx.x;
  const int lane = t & 63;
  const int w    = t >> 6;
  const int wm   = w >> 1;
  const int wn   = w & 1;
  const int row0 = blockIdx.y * BM;
  const int col0 = blockIdx.x * BN;
  const int lq   = lane & 15;
  const int lg   = lane >> 4;

  const int sr  = lane >> 3;
  const int sch = (lane & 7) ^ (sr & 7);
  const __bf16* aG = A + (size_t)(row0 + w * 32 + sr) * K + sch * 8;
  const __bf16* bG = B + (size_t)(col0 + w * 32 + sr) * K + sch * 8;
  __bf16* asW = As + w * 2048;
  __bf16* bsW = Bs + w * 2048;

  f32x4 acc[4][4];
#pragma unroll
  for (int i = 0; i < 4; ++i)
#pragma unroll
    for (int j = 0; j < 4; ++j) { acc[i][j][0]=0.f; acc[i][j][1]=0.f; acc[i][j][2]=0.f; acc[i][j][3]=0.f; }

  for (int kt = 0; kt < K; kt += BK) {
    __syncthreads();
#pragma unroll
    for (int seg = 0; seg < 4; ++seg) {
      GLOAD_LDS16(aG + (size_t)seg * 8 * K + kt, asW + seg * 512);
      GLOAD_LDS16(bG + (size_t)seg * 8 * K + kt, bsW + seg * 512);
    }
    __syncthreads();

#pragma unroll
    for (int kk = 0; kk < 2; ++kk) {
      const int ch = kk * 4 + lg;
      bf16x8 af[4], bfr[4];
#pragma unroll
      for (int mf = 0; mf < 4; ++mf) {
        int r = wm * 64 + mf * 16 + lq;
        af[mf] = *(const bf16x8*)(As + r * BK + ((ch ^ (r & 7)) * 8));
      }
#pragma unroll
      for (int nf = 0; nf < 4; ++nf) {
        int r = wn * 64 + nf * 16 + lq;
        bfr[nf] = *(const bf16x8*)(Bs + r * BK + ((ch ^ (r & 7)) * 8));
      }
#pragma unroll
      for (int mf = 0; mf < 4; ++mf)
#pragma unroll
        for (int nf = 0; nf < 4; ++nf)
          acc[mf][nf] = __builtin_amdgcn_mfma_f32_16x16x32_bf16(af[mf], bfr[nf], acc[mf][nf], 0, 0, 0);
    }
  }

#pragma unroll
  for (int mf = 0; mf < 4; ++mf) {
#pragma unroll
    for (int nf = 0; nf < 4; ++nf) {
      int col = col0 + wn * 64 + nf * 16 + lq;
      float bv = bias ? bias[col] : 0.0f;
#pragma unroll
      for (int r = 0; r < 4; ++r) {
        int rowg = row0 + wm * 64 + mf * 16 + lg * 4 + r;
        C[(size_t)rowg * N + col] = (OutT)(acc[mf][nf][r] + bv);
      }
    }
  }
}

// ---------------- RoPE on Q/K (bf16 in/out, compact bf16 table) ----------------
__global__ void rope_qk(const __bf16* __restrict__ qkv,
                        const __bf16* __restrict__ cosbf,
                        const __bf16* __restrict__ sinbf,
                        __bf16* __restrict__ Qo, __bf16* __restrict__ Ko)
{
  int i = blockIdx.x * blockDim.x + threadIdx.x;
  if (i >= S_LEN * 512) return;
  const int s   = i >> 9;
  const int col = (i & 511) * 8;
  const int d   = col & 127;

  const bf16x8 xv = *(const bf16x8*)(qkv + (size_t)s * NQKV + col);
  const int pcol  = col + ((d < 64) ? 64 : -64);
  const bf16x8 pv = *(const bf16x8*)(qkv + (size_t)s * NQKV + pcol);
  const float sgn = (d < 64) ? -1.0f : 1.0f;

  const bf16x8 cv = *(const bf16x8*)(cosbf + (size_t)s * HD + d);
  const bf16x8 sv = *(const bf16x8*)(sinbf + (size_t)s * HD + d);
  bf16x8 o;
#pragma unroll
  for (int j = 0; j < 8; ++j)
    o[j] = (__bf16)((float)xv[j] * (float)cv[j] + sgn * (float)pv[j] * (float)sv[j]);

  if (col < HID) {
    int h = col >> 7;
    *(bf16x8*)(Qo + ((size_t)h * S_LEN + s) * HD + d) = o;
  } else {
    int kh = (col - HID) >> 7;
    *(bf16x8*)(Ko + ((size_t)kh * S_LEN + s) * HD + d) = o;
  }
}

// ---------------- V transpose ----------------
__global__ __launch_bounds__(256) void v_transpose(const __bf16* __restrict__ qkv,
                                                   __bf16* __restrict__ Vt)
{
  __shared__ __bf16 tile[64][72];
  const int b   = blockIdx.x;
  const int kh  = b >> 6;
  const int s0  = ((b >> 1) & 31) * 64;
  const int d0  = (b & 1) * 64;
  const int t   = threadIdx.x;

#pragma unroll
  for (int p = 0; p < 2; ++p) {
    int sl = p * 32 + (t >> 3);
    int c  = t & 7;
    bf16x8 v = *(const bf16x8*)(qkv + (size_t)(s0 + sl) * NQKV + 4096 + kh * HD + d0 + c * 8);
#pragma unroll
    for (int j = 0; j < 8; ++j) tile[sl][c * 8 + j] = v[j];
  }
  __syncthreads();
#pragma unroll
  for (int p = 0; p < 2; ++p) {
    int idx = p * 256 + t;
    int dl  = idx >> 3;
    int sg  = idx & 7;
    bf16x8 o;
#pragma unroll
    for (int j = 0; j < 8; ++j) o[j] = tile[sg * 8 + j][dl];
    *(bf16x8*)(Vt + ((size_t)kh * HD + d0 + dl) * S_LEN + s0 + sg * 8) = o;
  }
}

// ---- KV-split piece table: 24 (qtile, seg) pieces per head, heavy-first ----
__device__ const unsigned char SEG_QT[24] = {7,8,9,10,11,12,13,14,15,15,14,6,13,5,12,4,11,3,10,2,9,1,8,0};
__device__ const unsigned char SEG_SG[24] = {0,0,0,0, 0, 0, 0, 0, 0, 1, 1,0, 1,0, 1,0, 1,0, 1,0,1,0,1,0};

// ---------------- Flash attention (KV-split, defer-max, lane-local softmax) ----------------
__global__ __launch_bounds__(512, 4) void attn_fwd(
    const __bf16* __restrict__ Q, const __bf16* __restrict__ K,
    const __bf16* __restrict__ Vt, __bf16* __restrict__ Opart,
    float* __restrict__ mlbuf)
{
  __shared__ __bf16 Ks[2][64 * HD];
  __shared__ __bf16 Vs[2][HD * 64];

  const int t     = threadIdx.x;
  const int lane  = t & 63;
  const int w     = t >> 6;
  const int pid   = blockIdx.x / NH;
  const int h     = blockIdx.x % NH;
  const int qtile = SEG_QT[pid];
  const int seg   = SEG_SG[pid];
  const int kvh   = h / GRP;
  const int q0w   = qtile * 128 + w * 16;
  const int lq    = lane & 15;
  const int lg    = lane >> 4;

  const int nkt_full = 2 * qtile + 2;
  const int kt0 = seg * 16;
  const int kt1 = (nkt_full < kt0 + 16) ? nkt_full : (kt0 + 16);

  const __bf16* Kbase = K  + (size_t)kvh * S_LEN * HD;
  const __bf16* Vbase = Vt + (size_t)kvh * HD * S_LEN;

  const int krow_in = lane >> 4;
  const int kch     = lane & 15;
  const int vrow_in = lane >> 3;
  const int vch     = lane & 7;

  bf16x8 qf[4];
  {
    const __bf16* qp = Q + ((size_t)h * S_LEN + q0w + lq) * HD + lg * 8;
#pragma unroll
    for (int dd = 0; dd < 4; ++dd) qf[dd] = *(const bf16x8*)(qp + dd * 32);
  }

  f32x4 of[8];
#pragma unroll
  for (int i = 0; i < 8; ++i) { of[i][0]=0.f; of[i][1]=0.f; of[i][2]=0.f; of[i][3]=0.f; }
  float m_run = -1e30f;
  float lsum  = 0.0f;

  const float kscale = 0.08838834764831845f * 1.4426950408889634f;
  const float THR = 11.0f;

  const int srcA = lq + 16 * ((2 * lg) & 3);
  const int srcB = lq + 16 * ((2 * lg + 1) & 3);
  const bool hisel = (lg >> 1) != 0;

#define STAGE_KV(ktile, b)                                                       \
  {                                                                              \
    _Pragma("unroll")                                                            \
    for (int j = 0; j < 2; ++j) {                                                \
      int rr = j * 32 + w * 4 + krow_in;                                         \
      int sc = kch ^ (rr & 15);                                                  \
      GLOAD_LDS16(Kbase + (size_t)((ktile) * 64 + rr) * HD + sc * 8,             \
                  &Ks[b][(j * 32 + w * 4) * HD]);                                \
    }                                                                            \
    _Pragma("unroll")                                                            \
    for (int j = 0; j < 2; ++j) {                                                \
      int rr = j * 64 + w * 8 + vrow_in;                                         \
      int sc = vch ^ (rr & 7);                                                   \
      GLOAD_LDS16(Vbase + (size_t)rr * S_LEN + (ktile) * 64 + sc * 8,            \
                  &Vs[b][(j * 64 + w * 8) * 64]);                                \
    }                                                                            \
  }

  STAGE_KV(kt0, 0);
  __syncthreads();

  int cur = 0;
  for (int kt = kt0; kt < kt1; ++kt) {
    if (kt + 1 < kt1) STAGE_KV(kt + 1, cur ^ 1);

    const bool active = (kt * 64) <= (q0w + 15);
    if (active) {
      const __bf16* KsC = &Ks[cur][0];
      const __bf16* VsC = &Vs[cur][0];

      f32x4 sf[4];
      __builtin_amdgcn_s_setprio(1);
#pragma unroll
      for (int kb = 0; kb < 4; ++kb) {
        sf[kb][0]=0.f; sf[kb][1]=0.f; sf[kb][2]=0.f; sf[kb][3]=0.f;
#pragma unroll
        for (int dd = 0; dd < 4; ++dd) {
          int r  = kb * 16 + lq;
          int ch = dd * 4 + lg;
          bf16x8 kf = *(const bf16x8*)(KsC + r * HD + ((ch ^ (r & 15)) * 8));
          sf[kb] = __builtin_amdgcn_mfma_f32_16x16x32_bf16(kf, qf[dd], sf[kb], 0, 0, 0);
        }
      }
      __builtin_amdgcn_s_setprio(0);

      const int qg = q0w + lq;
      const bool diag = (kt * 64 + 63) > q0w;
      float pmax = -1e30f;
#pragma unroll
      for (int kb = 0; kb < 4; ++kb) {
#pragma unroll
        for (int r = 0; r < 4; ++r) {
          float v = sf[kb][r] * kscale;
          if (diag) {
            int kg = kt * 64 + kb * 16 + lg * 4 + r;
            if (kg > qg) v = -1e30f;
          }
          sf[kb][r] = v;
          pmax = fmaxf(pmax, v);
        }
      }

      if (__any(pmax > m_run + THR)) {
        float pm = fmaxf(pmax, __shfl_xor(pmax, 16));
        pm = fmaxf(pm, __shfl_xor(pm, 32));
        const float mn = fmaxf(m_run, pm);
        const float e = exp2f(m_run - mn);
        m_run = mn;
        lsum *= e;
#pragma unroll
        for (int db = 0; db < 8; ++db) {
          of[db][0] *= e; of[db][1] *= e; of[db][2] *= e; of[db][3] *= e;
        }
      }

      float ps = 0.0f;
      uint32_t pk[4][2];
#pragma unroll
      for (int kb = 0; kb < 4; ++kb) {
        float p0 = exp2f(sf[kb][0] - m_run);
        float p1 = exp2f(sf[kb][1] - m_run);
        float p2 = exp2f(sf[kb][2] - m_run);
        float p3 = exp2f(sf[kb][3] - m_run);
        ps += (p0 + p1) + (p2 + p3);
        unsigned short b0 = __builtin_bit_cast(unsigned short, (__bf16)p0);
        unsigned short b1 = __builtin_bit_cast(unsigned short, (__bf16)p1);
        unsigned short b2 = __builtin_bit_cast(unsigned short, (__bf16)p2);
        unsigned short b3 = __builtin_bit_cast(unsigned short, (__bf16)p3);
        pk[kb][0] = (uint32_t)b0 | ((uint32_t)b1 << 16);
        pk[kb][1] = (uint32_t)b2 | ((uint32_t)b3 << 16);
      }
      lsum += ps;

      __builtin_amdgcn_s_setprio(1);
#pragma unroll
      for (int kc = 0; kc < 2; ++kc) {
        uint32_t a0 = __shfl((int)pk[kc * 2][0],     srcA);
        uint32_t a1 = __shfl((int)pk[kc * 2][1],     srcA);
        uint32_t b0 = __shfl((int)pk[kc * 2 + 1][0], srcA);
        uint32_t b1 = __shfl((int)pk[kc * 2 + 1][1], srcA);
        uint32_t c0 = __shfl((int)pk[kc * 2][0],     srcB);
        uint32_t c1 = __shfl((int)pk[kc * 2][1],     srcB);
        uint32_t d0 = __shfl((int)pk[kc * 2 + 1][0], srcB);
        uint32_t d1 = __shfl((int)pk[kc * 2 + 1][1], srcB);
        uint4 pu;
        pu.x = hisel ? b0 : a0;
        pu.y = hisel ? b1 : a1;
        pu.z = hisel ? d0 : c0;
        pu.w = hisel ? d1 : c1;
        bf16x8 pfrag = __builtin_bit_cast(bf16x8, pu);
#pragma unroll
        for (int db = 0; db < 8; ++db) {
          int vr = db * 16 + lq;
          int vc = kc * 4 + lg;
          bf16x8 vf = *(const bf16x8*)(VsC + vr * 64 + ((vc ^ (vr & 7)) * 8));
          of[db] = __builtin_amdgcn_mfma_f32_16x16x32_bf16(vf, pfrag, of[db], 0, 0, 0);
        }
      }
      __builtin_amdgcn_s_setprio(0);
    }

    __syncthreads();
    cur ^= 1;
  }
#undef STAGE_KV

  lsum += __shfl_xor(lsum, 16);
  lsum += __shfl_xor(lsum, 32);
  const float rl = 1.0f / lsum;
  const int q = q0w + lq;
  const size_t pbase = ((size_t)h * S_LEN + q) * 2 + seg;
  __bf16* op = Opart + pbase * HD + lg * 4;
#pragma unroll
  for (int db = 0; db < 8; ++db) {
    bf16x4 o4;
    o4[0] = (__bf16)(of[db][0] * rl);
    o4[1] = (__bf16)(of[db][1] * rl);
    o4[2] = (__bf16)(of[db][2] * rl);
    o4[3] = (__bf16)(of[db][3] * rl);
    *(bf16x4*)(op + db * 16) = o4;
  }
  if (lg == 0) {
    mlbuf[pbase * 2]     = m_run;
    mlbuf[pbase * 2 + 1] = lsum;
  }
}

// ---------------- combine partial attention outputs ----------------
__global__ __launch_bounds__(256) void attn_combine(
    const __bf16* __restrict__ Opart, const float* __restrict__ mlbuf,
    __bf16* __restrict__ Ao)
{
  const int gw   = (blockIdx.x * 256 + threadIdx.x) >> 6;
  const int lane = threadIdx.x & 63;
  if (gw >= NH * S_LEN) return;
  const int h  = gw >> 11;
  const int q  = gw & 2047;
  const int qt = q >> 7;
  const size_t base = ((size_t)h * S_LEN + q) * 2;

  const uint32_t x0 = ((const uint32_t*)(Opart + base * HD))[lane];
  const float lo0 = (float)__builtin_bit_cast(__bf16, (unsigned short)(x0 & 0xffff));
  const float hi0 = (float)__builtin_bit_cast(__bf16, (unsigned short)(x0 >> 16));

  float olo, ohi;
  if (qt >= 8) {
    const float m0 = mlbuf[base * 2],       l0 = mlbuf[base * 2 + 1];
    const float m1 = mlbuf[(base + 1) * 2], l1 = mlbuf[(base + 1) * 2 + 1];
    const uint32_t x1 = ((const uint32_t*)(Opart + (base + 1) * HD))[lane];
    const float lo1 = (float)__builtin_bit_cast(__bf16, (unsigned short)(x1 & 0xffff));
    const float hi1 = (float)__builtin_bit_cast(__bf16, (unsigned short)(x1 >> 16));
    const float M  = fmaxf(m0, m1);
    const float w0 = l0 * exp2f(m0 - M);
    const float w1 = l1 * exp2f(m1 - M);
    const float rs = 1.0f / (w0 + w1);
    olo = (w0 * lo0 + w1 * lo1) * rs;
    ohi = (w0 * hi0 + w1 * hi1) * rs;
  } else {
    olo = lo0; ohi = hi0;
  }

  const unsigned short blo = __builtin_bit_cast(unsigned short, (__bf16)olo);
  const unsigned short bhi = __builtin_bit_cast(unsigned short, (__bf16)ohi);
  ((uint32_t*)(Ao + (size_t)q * HID + h * HD))[lane] =
      (uint32_t)blo | ((uint32_t)bhi << 16);
}

// ---------------- launch ----------------
extern "C" void kernel_launch(void* const* d_in, const int* in_sizes, int n_in,
                              void* d_out, int out_size, void* d_ws, size_t ws_size,
                              hipStream_t stream) {
  const float* hidden = (const float*)d_in[0];
  const float* cosb   = (const float*)d_in[1];
  const float* sinb   = (const float*)d_in[2];
  const float* q_w = (const float*)d_in[4];
  const float* q_b = (const float*)d_in[5];
  const float* k_w = (const float*)d_in[6];
  const float* k_b = (const float*)d_in[7];
  const float* v_w = (const float*)d_in[8];
  const float* v_b = (const float*)d_in[9];
  const float* o_w = (const float*)d_in[10];
  float* out = (float*)d_out;

  char* ws = (char*)d_ws;
  size_t off = 0;
  auto alloc = [&](size_t bytes) {
    off = (off + 255) & ~(size_t)255;
    void* p = ws + off;
    off += bytes;
    return p;
  };

  __bf16* hid_bf  = (__bf16*)alloc((size_t)S_LEN * HID * 2);
  __bf16* Wqkv    = (__bf16*)alloc((size_t)NQKV * HID * 2);
  float*  bias    = (float*) alloc((size_t)NQKV * 4);
  __bf16* qkv_bf  = (__bf16*)alloc((size_t)S_LEN * NQKV * 2);
  __bf16* Qb      = (__bf16*)alloc((size_t)NH * S_LEN * HD * 2);
  __bf16* Kb      = (__bf16*)alloc((size_t)NKV * S_LEN * HD * 2);
  __bf16* Vtb     = (__bf16*)alloc((size_t)NKV * HD * S_LEN * 2);
  __bf16* attn_o  = (__bf16*)alloc((size_t)S_LEN * HID * 2);
  __bf16* ow_bf   = (__bf16*)alloc((size_t)HID * HID * 2);
  __bf16* cosbf   = (__bf16*)alloc((size_t)S_LEN * HD * 2);
  __bf16* sinbf   = (__bf16*)alloc((size_t)S_LEN * HD * 2);

  // KV-split partial buffers overlay hid_bf/Wqkv (dead once attn_fwd runs).
  __bf16* Opart = (__bf16*)(ws);
  float*  mlbuf = (float*)(ws + ((size_t)34 << 20));

  const int TB = 256;
  auto cdiv = [](int a, int b) { return (a + b - 1) / b; };

  // fused conversions + bias concat + rope table (single launch)
  {
    const int n8 = (S_LEN * HID + 2 * HID * HID + 2 * 512 * HID) / 8 + S_LEN * 16;
    cvt_all<<<cdiv(n8, TB), TB, 0, stream>>>(hidden, q_w, k_w, v_w, o_w,
                                             q_b, k_b, v_b, cosb, sinb,
                                             hid_bf, Wqkv, ow_bf, bias,
                                             cosbf, sinbf);
  }

  // QKV projection (bf16 out, bias fused)
  {
    dim3 grid(NQKV / BN, S_LEN / BM);
    gemm_bt<__bf16><<<grid, TB, 0, stream>>>(hid_bf, Wqkv, bias, qkv_bf, S_LEN, NQKV, HID);
  }

  // RoPE (Q,K) + V transpose
  {
    int n = S_LEN * 512;
    rope_qk<<<cdiv(n, TB), TB, 0, stream>>>(qkv_bf, cosbf, sinbf, Qb, Kb);
    v_transpose<<<NKV * 32 * 2, TB, 0, stream>>>(qkv_bf, Vtb);
  }

  // flash attention: KV-split pieces (24 per head), heavy-first
  attn_fwd<<<24 * NH, 512, 0, stream>>>(Qb, Kb, Vtb, Opart, mlbuf);

  // merge partials
  attn_combine<<<cdiv(NH * S_LEN, 4), TB, 0, stream>>>(Opart, mlbuf, attn_o);

  // output projection (f32 out)
  {
    dim3 grid(HID / BN, S_LEN / BM);
    gemm_bt<float><<<grid, TB, 0, stream>>>(attn_o, ow_bf, nullptr, out, S_LEN, HID, HID);
  }
}